// Round 14
// baseline (303.565 us; speedup 1.0000x reference)
//
#include <hip/hip_runtime.h>
#include <cstdint>
#include <cstddef>

#define NNODE 100000
#define NEDGE 1600000
#define INC   128
#define HC    128     // H*C
#define NH    4
#define CPH   32
#define NPART 8       // XCD count; edge partition p = blockIdx & 7
#define NP8   (NNODE * NPART)
#define SLOPE 0.2f
#define KP    136     // padded K stride (halves) for LDS tiles
#define NCHUNK ((NNODE + 63) / 64)   // 1563

#define LRELU(v) fmaxf((v), SLOPE*(v))

typedef _Float16 half4 __attribute__((ext_vector_type(4)));
typedef _Float16 f16x8 __attribute__((ext_vector_type(8)));
typedef float    f32x4 __attribute__((ext_vector_type(4)));

static inline size_t align256(size_t x){ return (x + 255) & ~(size_t)255; }

// ---------------------------------------------------------------------------
// W [128k][128c] f32 -> wt16 [c][k] fp16 (transposed, unpadded in global).
// ---------------------------------------------------------------------------
__global__ void wprep_kernel(const float* __restrict__ W, _Float16* __restrict__ wt16)
{
    const int idx = blockIdx.x * 256 + threadIdx.x;   // 16384
    const int k = idx >> 7, c = idx & 127;
    wt16[c * 128 + k] = (_Float16)W[k * 128 + c];
}

// ---------------------------------------------------------------------------
// proj: xp16 = fp16(x @ W) via MFMA f16 (f32 accum) + FUSED per-node logits.
// Grid-stride over 64-row chunks; W^T staged in LDS once per block.
// Block 256 = 4 waves; wave w -> rows 16w..16w+15 x 128 cols per chunk.
// A-frag: x_s[row=l15][k=q*8+i]. B-frag: wt_s[col][k] (B^T -> k-contiguous).
// C/D (m89): col=16n+l15, row=q*4+r.
// Logits from acc registers: head h = n>>1; reduce over the 16-lane l15 group.
// ---------------------------------------------------------------------------
__global__ __launch_bounds__(256) void proj_kernel(
    const float* __restrict__ x, const _Float16* __restrict__ wt16,
    const float* __restrict__ att_src, const float* __restrict__ att_dst,
    _Float16* __restrict__ xp16, float* __restrict__ a_src,
    float* __restrict__ a_dst)
{
    __shared__ _Float16 wt_s[128 * KP];   // 34816 B
    __shared__ _Float16 x_s[64 * KP];     // 17408 B

    const int tid  = threadIdx.x;
    const int lane = tid & 63;
    const int w    = tid >> 6;
    const int l15  = lane & 15;
    const int q    = lane >> 4;

    // stage W^T once per block: 16384 halves, 16 x half4 per thread
    #pragma unroll
    for (int i = 0; i < 16; ++i) {
        const int idx = i * 256 + tid;          // half4 index
        const int r = idx >> 5, c4 = idx & 31;
        *(half4*)(wt_s + r * KP + c4 * 4) = *(const half4*)(wt16 + r * 128 + c4 * 4);
    }

    // per-lane attention vectors (uniform over chunks)
    float ats[8], atd[8];
    #pragma unroll
    for (int n = 0; n < 8; ++n) {
        ats[n] = att_src[16 * n + l15];
        atd[n] = att_dst[16 * n + l15];
    }

    for (int chunk = blockIdx.x; chunk < NCHUNK; chunk += gridDim.x) {
        const int row0 = chunk * 64;
        __syncthreads();   // protect x_s (prior stores read it) + wt_s first use

        // stage x rows -> fp16: 8 x float4 per thread
        #pragma unroll
        for (int i = 0; i < 8; ++i) {
            const int idx = i * 256 + tid;      // float4 index
            const int r = idx >> 5, c4 = idx & 31;
            const int row = row0 + r;
            half4 hv;
            if (row < NNODE) {
                const float4 v = *(const float4*)(x + (size_t)row * INC + c4 * 4);
                hv = half4{(_Float16)v.x, (_Float16)v.y, (_Float16)v.z, (_Float16)v.w};
            } else {
                hv = half4{(_Float16)0.f, (_Float16)0.f, (_Float16)0.f, (_Float16)0.f};
            }
            *(half4*)(x_s + r * KP + c4 * 4) = hv;
        }
        __syncthreads();

        f32x4 acc[8];
        #pragma unroll
        for (int n = 0; n < 8; ++n) acc[n] = f32x4{0.f, 0.f, 0.f, 0.f};

        #pragma unroll
        for (int kc = 0; kc < 4; ++kc) {
            const f16x8 a = *(const f16x8*)(x_s + (16 * w + l15) * KP + kc * 32 + q * 8);
            #pragma unroll
            for (int n = 0; n < 8; ++n) {
                const f16x8 b = *(const f16x8*)(wt_s + (16 * n + l15) * KP + kc * 32 + q * 8);
                acc[n] = __builtin_amdgcn_mfma_f32_16x16x32_f16(a, b, acc[n], 0, 0, 0);
            }
        }

        // fused logits from f32 accumulators
        #pragma unroll
        for (int h = 0; h < 4; ++h) {
            #pragma unroll
            for (int r = 0; r < 4; ++r) {
                float s = acc[2*h][r] * ats[2*h] + acc[2*h+1][r] * ats[2*h+1];
                float d = acc[2*h][r] * atd[2*h] + acc[2*h+1][r] * atd[2*h+1];
                s += __shfl_xor(s, 1); s += __shfl_xor(s, 2);
                s += __shfl_xor(s, 4); s += __shfl_xor(s, 8);
                d += __shfl_xor(d, 1); d += __shfl_xor(d, 2);
                d += __shfl_xor(d, 4); d += __shfl_xor(d, 8);
                if (l15 == 0) {
                    const int row = row0 + 16 * w + q * 4 + r;
                    if (row < NNODE) {
                        a_src[(size_t)row * NH + h] = s;
                        a_dst[(size_t)row * NH + h] = d;
                    }
                }
            }
        }

        __syncthreads();   // MFMA x_s reads done before repack overwrites
        // repack: wave w writes its own rows 16w + q*4 + r, cols 16n + l15
        #pragma unroll
        for (int n = 0; n < 8; ++n)
            #pragma unroll
            for (int r = 0; r < 4; ++r)
                x_s[(16 * w + q * 4 + r) * KP + 16 * n + l15] = (_Float16)acc[n][r];
        __syncthreads();

        // coalesced store: 8 x half4 per thread
        #pragma unroll
        for (int i = 0; i < 8; ++i) {
            const int idx = i * 256 + tid;      // half4 index
            const int r = idx >> 5, c4 = idx & 31;
            const int row = row0 + r;
            if (row < NNODE)
                *(half4*)(xp16 + (size_t)row * HC + c4 * 4) = *(const half4*)(x_s + r * KP + c4 * 4);
        }
    }
}

// ---------------------------------------------------------------------------
// CSR build, XCD-partitioned (unchanged, measured-good).
// ---------------------------------------------------------------------------
__global__ void count_seq_kernel(const int* __restrict__ ei,
                                 int* __restrict__ deg,
                                 int* __restrict__ seq)
{
    const int t4 = (blockIdx.x * 256 + threadIdx.x) * 4;
    const int p = blockIdx.x & (NPART - 1);
    if (t4 < NEDGE) {
        const int4 d4 = *(const int4*)(ei + NEDGE + t4);
        int4 s4;
        s4.x = atomicAdd(&deg[p * NNODE + d4.x], 1);
        s4.y = atomicAdd(&deg[p * NNODE + d4.y], 1);
        s4.z = atomicAdd(&deg[p * NNODE + d4.z], 1);
        s4.w = atomicAdd(&deg[p * NNODE + d4.w], 1);
        *(int4*)(seq + t4) = s4;
    }
}

__global__ __launch_bounds__(256) void scan_sums_kernel(
    const int* __restrict__ deg, int* __restrict__ bsums)
{
    __shared__ int lds[4];
    const int tid = threadIdx.x, lane = tid & 63, wid = tid >> 6;
    const int base = blockIdx.x * 4096 + tid * 16;
    int s = 0;
    #pragma unroll
    for (int i = 0; i < 16; ++i) {
        const int idx = base + i;
        if (idx < NP8) s += deg[idx];
    }
    #pragma unroll
    for (int off = 32; off; off >>= 1) s += __shfl_xor(s, off);
    if (lane == 0) lds[wid] = s;
    __syncthreads();
    if (tid == 0) bsums[blockIdx.x] = lds[0] + lds[1] + lds[2] + lds[3];
}

__global__ __launch_bounds__(256) void scan_partials_kernel(
    int* __restrict__ bsums, int nb)
{
    __shared__ int lds[4];
    const int tid = threadIdx.x, lane = tid & 63, wid = tid >> 6;
    const int v = (tid < nb) ? bsums[tid] : 0;
    int incl = v;
    #pragma unroll
    for (int off = 1; off < 64; off <<= 1) {
        const int u = __shfl_up(incl, off);
        if (lane >= off) incl += u;
    }
    if (lane == 63) lds[wid] = incl;
    __syncthreads();
    int wb = 0;
    for (int w = 0; w < wid; ++w) wb += lds[w];
    if (tid < nb) bsums[tid] = wb + incl - v;   // exclusive
}

__global__ __launch_bounds__(256) void scan_final_kernel(
    const int* __restrict__ deg, const int* __restrict__ bsums,
    int* __restrict__ offs)
{
    __shared__ int lds[4];
    const int tid = threadIdx.x, lane = tid & 63, wid = tid >> 6;
    const int base = blockIdx.x * 4096 + tid * 16;
    int v[16]; int s = 0;
    #pragma unroll
    for (int i = 0; i < 16; ++i) {
        const int idx = base + i;
        v[i] = (idx < NP8) ? deg[idx] : 0;
        s += v[i];
    }
    int incl = s;
    #pragma unroll
    for (int off = 1; off < 64; off <<= 1) {
        const int u = __shfl_up(incl, off);
        if (lane >= off) incl += u;
    }
    if (lane == 63) lds[wid] = incl;
    __syncthreads();
    int wb = 0;
    for (int w = 0; w < wid; ++w) wb += lds[w];
    int excl = bsums[blockIdx.x] + wb + incl - s;
    #pragma unroll
    for (int i = 0; i < 16; ++i) {
        const int idx = base + i;
        if (idx < NP8) offs[idx] = excl;
        excl += v[i];
    }
    if (blockIdx.x == 0 && tid == 0) offs[NP8] = NEDGE;
}

__global__ void scatter_kernel(const int* __restrict__ ei,
                               const int* __restrict__ offs,
                               const int* __restrict__ seq,
                               int* __restrict__ csr)
{
    const int t4 = (blockIdx.x * 256 + threadIdx.x) * 4;
    const int p = blockIdx.x & (NPART - 1);
    if (t4 < NEDGE) {
        const int4 d4 = *(const int4*)(ei + NEDGE + t4);
        const int4 s4 = *(const int4*)(ei + t4);
        const int4 q4 = *(const int4*)(seq + t4);
        csr[offs[p * NNODE + d4.x] + q4.x] = s4.x;
        csr[offs[p * NNODE + d4.y] + q4.y] = s4.y;
        csr[offs[p * NNODE + d4.z] + q4.z] = s4.z;
        csr[offs[p * NNODE + d4.w] + q4.w] = s4.w;
    }
}

// ---------------------------------------------------------------------------
// Aggregation (unchanged, measured: ~77 us, delivered-bytes bound at fp16).
// ---------------------------------------------------------------------------
__global__ __launch_bounds__(256) void aggregate_kernel(
    const _Float16* __restrict__ xp16, const float* __restrict__ a_src,
    const float* __restrict__ a_dst, const int* __restrict__ offs,
    const int* __restrict__ csr, const float* __restrict__ bias,
    float* __restrict__ out)
{
    __shared__ float p_lds[4][2][32][4];
    __shared__ int   j_lds[4][2][32];

    const int lane = threadIdx.x & 63;
    const int wid  = threadIdx.x >> 6;
    const int half = lane >> 5;
    const int sl   = lane & 31;
    const int node = blockIdx.x * 8 + wid * 2 + half;
    const int h    = sl >> 3;

    int s_val = 0, len = 0;
    if (sl < 8) {
        const int o0 = offs[sl * NNODE + node];
        const int o1 = offs[sl * NNODE + node + 1];
        s_val = o0; len = o1 - o0;
    }
    int incl = len;
    #pragma unroll
    for (int o = 1; o < 8; o <<= 1) {
        const int u = __shfl_up(incl, o, 32);
        if (sl >= o) incl += u;
    }
    const int excl = incl - len;
    int s_arr[8], b_arr[8];
    #pragma unroll
    for (int q = 0; q < 8; ++q) {
        s_arr[q] = __shfl(s_val, q, 32);
        b_arr[q] = __shfl(excl,  q, 32);
    }
    const int D = __shfl(incl, 7, 32);

    const float4 ad = ((const float4*)a_dst)[node];
    const float4 as = ((const float4*)a_src)[node];

    const float lself = (h == 0) ? LRELU(as.x + ad.x)
                      : (h == 1) ? LRELU(as.y + ad.y)
                      : (h == 2) ? LRELU(as.z + ad.z)
                                 : LRELU(as.w + ad.w);
    const float pself = __expf(lself);
    float den = pself;
    float4 acc;
    {
        const half4 hv = *(const half4*)(xp16 + (size_t)node * HC + 4 * sl);
        acc.x = pself * (float)hv.x; acc.y = pself * (float)hv.y;
        acc.z = pself * (float)hv.z; acc.w = pself * (float)hv.w;
    }

    float* pme = &p_lds[wid][half][sl][0];
    int*   jme = &j_lds[wid][half][sl];
    const float* pw = &p_lds[wid][half][0][h];
    const int*   jw = &j_lds[wid][half][0];

    for (int base = 0; base < D; base += 32) {
        const int cnt = min(32, D - base);
        if (sl < cnt) {
            const int v = base + sl;
            int sp = s_arr[0], ex = b_arr[0];
            #pragma unroll
            for (int q = 1; q < 8; ++q) {
                const bool c = (v >= b_arr[q]);
                sp = c ? s_arr[q] : sp;
                ex = c ? b_arr[q] : ex;
            }
            const int j = csr[sp + v - ex];
            const float4 aj = ((const float4*)a_src)[j];
            const float p0 = __expf(LRELU(aj.x + ad.x));
            const float p1 = __expf(LRELU(aj.y + ad.y));
            const float p2 = __expf(LRELU(aj.z + ad.z));
            const float p3 = __expf(LRELU(aj.w + ad.w));
            *(float4*)pme = make_float4(p0, p1, p2, p3);
            *jme = j;
        }

        asm volatile("s_waitcnt lgkmcnt(0)" ::: "memory");

        int t = 0;
        for (; t + 3 < cnt; t += 4) {
            const int j0 = jw[t], j1 = jw[t+1], j2 = jw[t+2], j3 = jw[t+3];
            const float q0 = pw[4*t], q1 = pw[4*t+4], q2 = pw[4*t+8], q3 = pw[4*t+12];
            const half4 v0 = *(const half4*)(xp16 + (size_t)j0 * HC + 4 * sl);
            const half4 v1 = *(const half4*)(xp16 + (size_t)j1 * HC + 4 * sl);
            const half4 v2 = *(const half4*)(xp16 + (size_t)j2 * HC + 4 * sl);
            const half4 v3 = *(const half4*)(xp16 + (size_t)j3 * HC + 4 * sl);
            den += q0 + q1 + q2 + q3;
            acc.x = fmaf(q0, (float)v0.x, acc.x); acc.y = fmaf(q0, (float)v0.y, acc.y);
            acc.z = fmaf(q0, (float)v0.z, acc.z); acc.w = fmaf(q0, (float)v0.w, acc.w);
            acc.x = fmaf(q1, (float)v1.x, acc.x); acc.y = fmaf(q1, (float)v1.y, acc.y);
            acc.z = fmaf(q1, (float)v1.z, acc.z); acc.w = fmaf(q1, (float)v1.w, acc.w);
            acc.x = fmaf(q2, (float)v2.x, acc.x); acc.y = fmaf(q2, (float)v2.y, acc.y);
            acc.z = fmaf(q2, (float)v2.z, acc.z); acc.w = fmaf(q2, (float)v2.w, acc.w);
            acc.x = fmaf(q3, (float)v3.x, acc.x); acc.y = fmaf(q3, (float)v3.y, acc.y);
            acc.z = fmaf(q3, (float)v3.z, acc.z); acc.w = fmaf(q3, (float)v3.w, acc.w);
        }
        for (; t < cnt; ++t) {
            const int   jt = jw[t];
            const float pt = pw[4*t];
            const half4 hv = *(const half4*)(xp16 + (size_t)jt * HC + 4 * sl);
            den += pt;
            acc.x = fmaf(pt, (float)hv.x, acc.x); acc.y = fmaf(pt, (float)hv.y, acc.y);
            acc.z = fmaf(pt, (float)hv.z, acc.z); acc.w = fmaf(pt, (float)hv.w, acc.w);
        }
    }

    const float inv = 1.0f / den;
    float4 r;
    r.x = acc.x * inv; r.y = acc.y * inv; r.z = acc.z * inv; r.w = acc.w * inv;
    r.x += __shfl_xor(r.x, 8); r.x += __shfl_xor(r.x, 16);
    r.y += __shfl_xor(r.y, 8); r.y += __shfl_xor(r.y, 16);
    r.z += __shfl_xor(r.z, 8); r.z += __shfl_xor(r.z, 16);
    r.w += __shfl_xor(r.w, 8); r.w += __shfl_xor(r.w, 16);
    if (sl < 8) {
        const float4 b = ((const float4*)bias)[sl];
        float4 o;
        o.x = fmaxf(0.25f * r.x + b.x, 0.f);
        o.y = fmaxf(0.25f * r.y + b.y, 0.f);
        o.z = fmaxf(0.25f * r.z + b.z, 0.f);
        o.w = fmaxf(0.25f * r.w + b.w, 0.f);
        *(float4*)(out + (size_t)node * CPH + 4 * sl) = o;
    }
}

// ---------------------------------------------------------------------------
extern "C" void kernel_launch(void* const* d_in, const int* in_sizes, int n_in,
                              void* d_out, int out_size, void* d_ws, size_t ws_size,
                              hipStream_t stream)
{
    const float* x       = (const float*)d_in[0];
    const int*   ei      = (const int*)d_in[1];
    const float* W       = (const float*)d_in[2];
    const float* att_src = (const float*)d_in[3];
    const float* att_dst = (const float*)d_in[4];
    const float* bias    = (const float*)d_in[5];
    float*       out     = (float*)d_out;

    char* ws = (char*)d_ws;
    size_t off = 0;
    auto alloc = [&](size_t bytes) -> void* {
        void* p = ws + off;
        off = align256(off + bytes);
        return p;
    };
    _Float16* xp16 = (_Float16*)alloc((size_t)NNODE * HC * sizeof(_Float16));
    _Float16* wt16 = (_Float16*)alloc((size_t)HC * INC * sizeof(_Float16));
    float* a_src  = (float*)alloc((size_t)NNODE * NH * sizeof(float));
    float* a_dst  = (float*)alloc((size_t)NNODE * NH * sizeof(float));
    int*   deg    = (int*)alloc((size_t)NP8 * sizeof(int));
    int*   seq    = (int*)alloc((size_t)NEDGE * sizeof(int));
    int*   offs   = (int*)alloc((size_t)(NP8 + 1) * sizeof(int));
    int*   csr    = (int*)alloc((size_t)NEDGE * sizeof(int));
    int*   bsums  = (int*)alloc(1024);

    hipMemsetAsync(deg, 0, (size_t)NP8 * sizeof(int), stream);

    wprep_kernel<<<64, 256, 0, stream>>>(W, wt16);
    proj_kernel<<<512, 256, 0, stream>>>(x, wt16, att_src, att_dst, xp16, a_src, a_dst);

    constexpr int EB = (NEDGE / 4 + 255) / 256;   // 1563 blocks, 1024 edges each
    count_seq_kernel<<<EB, 256, 0, stream>>>(ei, deg, seq);

    constexpr int NB = (NP8 + 4095) / 4096;   // 196
    scan_sums_kernel<<<NB, 256, 0, stream>>>(deg, bsums);
    scan_partials_kernel<<<1, 256, 0, stream>>>(bsums, NB);
    scan_final_kernel<<<NB, 256, 0, stream>>>(deg, bsums, offs);

    scatter_kernel<<<EB, 256, 0, stream>>>(ei, offs, seq, csr);
    aggregate_kernel<<<NNODE / 8, 256, 0, stream>>>(xp16, a_src, a_dst, offs, csr, bias, out);
}